// Round 9
// baseline (321.693 us; speedup 1.0000x reference)
//
#include <hip/hip_runtime.h>
#include <hip/hip_bf16.h>
#include <math.h>

// ---- types ----
typedef __bf16 bf16_t;
typedef bf16_t bf16x8 __attribute__((ext_vector_type(8)));
typedef float f32x4 __attribute__((ext_vector_type(4)));

#define D_MODEL 1024
#define NH 16
#define DK 64
#define SEQ 2048
#define MROWS 4096   // B*S
#define LDP 72       // padded LDS row (bf16) for attn tiles
#define LDSW 64      // UNPADDED row width for async-DMA GEMM tiles (XOR-swizzled)
#define LDC 136      // padded row for the 128x128 epilogue staging tile

__device__ __forceinline__ bf16x8 ldfrag(const bf16_t* p) {
    union { uint4 u; bf16x8 v; } c;
    c.u = *reinterpret_cast<const uint4*>(p);
    return c.v;
}

__device__ __forceinline__ f32x4 zero4() { f32x4 z = {0.f, 0.f, 0.f, 0.f}; return z; }

// async global->LDS DMA, 16B per lane. LDS dest = wave-uniform base + lane*16.
__device__ __forceinline__ void gll16(const bf16_t* g, bf16_t* l) {
    __builtin_amdgcn_global_load_lds(
        (const __attribute__((address_space(1))) unsigned int*)g,
        (__attribute__((address_space(3))) unsigned int*)l,
        16, 0, 0);
}

// ---- fp32 -> bf16 pack, 3 tensors via blockIdx.y ----
__global__ void pack3(const float* __restrict__ a, const float* __restrict__ b,
                      const float* __restrict__ c,
                      bf16_t* __restrict__ da, bf16_t* __restrict__ db, bf16_t* __restrict__ dc) {
    const float* s = (blockIdx.y == 0) ? a : (blockIdx.y == 1) ? b : c;
    bf16_t* d      = (blockIdx.y == 0) ? da : (blockIdx.y == 1) ? db : dc;
    int i = (blockIdx.x * blockDim.x + threadIdx.x) * 4;
    float4 f = *reinterpret_cast<const float4*>(s + i);
    union { bf16_t h[4]; uint2 u; } o;
    o.h[0] = (bf16_t)f.x; o.h[1] = (bf16_t)f.y; o.h[2] = (bf16_t)f.z; o.h[3] = (bf16_t)f.w;
    *reinterpret_cast<uint2*>(d + i) = o.u;
}

// ---- fp32 -> bf16 pack, 4 weight matrices via blockIdx.y ----
__global__ void pack4(const float* __restrict__ a, const float* __restrict__ b,
                      const float* __restrict__ c, const float* __restrict__ e,
                      bf16_t* __restrict__ da, bf16_t* __restrict__ db,
                      bf16_t* __restrict__ dc, bf16_t* __restrict__ de) {
    const float* s = (blockIdx.y == 0) ? a : (blockIdx.y == 1) ? b : (blockIdx.y == 2) ? c : e;
    bf16_t* d      = (blockIdx.y == 0) ? da : (blockIdx.y == 1) ? db : (blockIdx.y == 2) ? dc : de;
    int i = (blockIdx.x * blockDim.x + threadIdx.x) * 4;
    float4 f = *reinterpret_cast<const float4*>(s + i);
    union { bf16_t h[4]; uint2 u; } o;
    o.h[0] = (bf16_t)f.x; o.h[1] = (bf16_t)f.y; o.h[2] = (bf16_t)f.z; o.h[3] = (bf16_t)f.w;
    *reinterpret_cast<uint2*>(d + i) = o.u;
}

// ---- shared GEMM core: C(128x128) = A(rowmaj MxK) * B(rowmaj NxK)^T ----
// m97 structure: async global_load_lds (width 16) staging — NO staging VGPRs,
// so nothing to spill. LDS tiles unpadded [128][64] with XOR chunk swizzle.
__device__ __forceinline__ void gemm_core(
    const bf16_t* __restrict__ A, const bf16_t* __restrict__ Bm,
    int K, int m0, int n0,
    bf16_t* As, bf16_t* Bs,       // each 128*LDSW bf16
    f32x4 acc[4][4]) {

    const int tid = threadIdx.x;
    const int lane = tid & 63;
    const int wid = tid >> 6;
    const int wm = (wid >> 1) * 64, wn = (wid & 1) * 64;
    const int l15 = lane & 15, quad = lane >> 4;

    const int lrow   = lane >> 3;                // 0..7 row within 8-row group
    const int gcol   = ((lane & 7) ^ lrow) * 8;  // swizzled logical col (elems)

    #pragma unroll
    for (int i = 0; i < 4; i++)
        #pragma unroll
        for (int j = 0; j < 4; j++) acc[i][j] = zero4();

    for (int k0 = 0; k0 < K; k0 += 64) {
        __syncthreads();
        #pragma unroll
        for (int t = 0; t < 4; t++) {
            const int rbase = wid * 32 + t * 8;
            gll16(A  + (size_t)(m0 + rbase + lrow) * K + k0 + gcol, As + rbase * LDSW);
            gll16(Bm + (size_t)(n0 + rbase + lrow) * K + k0 + gcol, Bs + rbase * LDSW);
        }
        __syncthreads();
        #pragma unroll
        for (int c = 0; c < 2; c++) {
            bf16x8 af[4], bfr[4];
            #pragma unroll
            for (int i = 0; i < 4; i++) {
                const int row = wm + i * 16 + l15;
                const int pc = ((c * 4 + quad) ^ (l15 & 7)) * 8;
                af[i] = ldfrag(As + row * LDSW + pc);
            }
            #pragma unroll
            for (int j = 0; j < 4; j++) {
                const int row = wn + j * 16 + l15;
                const int pc = ((c * 4 + quad) ^ (l15 & 7)) * 8;
                bfr[j] = ldfrag(Bs + row * LDSW + pc);
            }
            #pragma unroll
            for (int i = 0; i < 4; i++)
                #pragma unroll
                for (int j = 0; j < 4; j++)
                    acc[i][j] = __builtin_amdgcn_mfma_f32_16x16x32_bf16(af[i], bfr[j], acc[i][j], 0, 0, 0);
        }
    }
}

// ---- fused Q/K/V projection: blockIdx.z picks which ----
__global__ __launch_bounds__(256, 2) void proj_gemm(
    const bf16_t* __restrict__ qb, const bf16_t* __restrict__ kb,
    const bf16_t* __restrict__ vb,
    const bf16_t* __restrict__ Wq, const bf16_t* __restrict__ Wk,
    const bf16_t* __restrict__ Wv,
    const float* __restrict__ bq, const float* __restrict__ bk, const float* __restrict__ bv,
    bf16_t* __restrict__ Qh, bf16_t* __restrict__ Kh, bf16_t* __restrict__ Vt) {

    __shared__ __align__(16) bf16_t sm[128 * LDC];   // 34816B: As|Bs, reused as Cs
    bf16_t* As = sm;
    bf16_t* Bs = sm + 128 * LDSW;
    bf16_t (*Cs)[LDC] = reinterpret_cast<bf16_t(*)[LDC]>(sm);
    f32x4 acc[4][4];

    const int mode = blockIdx.z;
    const bf16_t* X = (mode == 0) ? qb : (mode == 1) ? kb : vb;
    const bf16_t* W = (mode == 0) ? Wq : (mode == 1) ? Wk : Wv;
    const float* bias = (mode == 0) ? bq : (mode == 1) ? bk : bv;
    const int m0 = blockIdx.y * 128, n0 = blockIdx.x * 128;

    gemm_core(X, W, D_MODEL, m0, n0, As, Bs, acc);

    const int tid = threadIdx.x, lane = tid & 63, wid = tid >> 6;
    const int wm = (wid >> 1) * 64, wn = (wid & 1) * 64;
    const int l15 = lane & 15, quad = lane >> 4;

    __syncthreads();
    if (mode != 2) {
        // Q gets 1/sqrt(dk) * log2(e) folded in so attn can use raw exp2
        const float sc = (mode == 0) ? 0.125f * 1.44269504f : 1.0f;
        #pragma unroll
        for (int i = 0; i < 4; i++)
            #pragma unroll
            for (int j = 0; j < 4; j++)
                #pragma unroll
                for (int r = 0; r < 4; r++) {
                    int gn = n0 + wn + j * 16 + l15;
                    Cs[wm + i * 16 + quad * 4 + r][wn + j * 16 + l15] =
                        (bf16_t)((acc[i][j][r] + bias[gn]) * sc);
                }
    } else {
        #pragma unroll
        for (int i = 0; i < 4; i++)
            #pragma unroll
            for (int j = 0; j < 4; j++)
                #pragma unroll
                for (int r = 0; r < 4; r++) {
                    int gn = n0 + wn + j * 16 + l15;
                    Cs[wn + j * 16 + l15][wm + i * 16 + quad * 4 + r] =
                        (bf16_t)(acc[i][j][r] + bias[gn]);
                }
    }
    __syncthreads();

    #pragma unroll
    for (int c = tid; c < 2048; c += 256) {
        int row = c >> 4, col8 = (c & 15) << 3;
        uint4 val = *reinterpret_cast<const uint4*>(&Cs[row][col8]);
        if (mode != 2) {
            int gm = m0 + row, gn = n0 + col8;
            int b = gm >> 11, seq = gm & 2047;
            int h = gn >> 6, dk = gn & 63;
            bf16_t* dst = (mode == 0) ? Qh : Kh;
            *reinterpret_cast<uint4*>(dst + ((size_t)(b * NH + h) * SEQ + seq) * DK + dk) = val;
        } else {
            int gn = n0 + row, gm = m0 + col8;
            int b = gm >> 11, seq = gm & 2047;
            int h = gn >> 6, dk = gn & 63;
            *reinterpret_cast<uint4*>(Vt + ((size_t)(b * NH + h) * DK + dk) * SEQ + seq) = val;
        }
    }
}

// ---- output projection: fp32 out + bias ----
__global__ __launch_bounds__(256, 2) void out_gemm(
    const bf16_t* __restrict__ Oc, const bf16_t* __restrict__ Wo,
    const float* __restrict__ bo, float* __restrict__ Cout) {

    __shared__ __align__(16) bf16_t As[128 * LDSW];
    __shared__ __align__(16) bf16_t Bs[128 * LDSW];
    f32x4 acc[4][4];
    const int m0 = blockIdx.y * 128, n0 = blockIdx.x * 128;

    gemm_core(Oc, Wo, D_MODEL, m0, n0, As, Bs, acc);

    const int tid = threadIdx.x, lane = tid & 63, wid = tid >> 6;
    const int wm = (wid >> 1) * 64, wn = (wid & 1) * 64;
    const int l15 = lane & 15, quad = lane >> 4;

    #pragma unroll
    for (int i = 0; i < 4; i++)
        #pragma unroll
        for (int j = 0; j < 4; j++)
            #pragma unroll
            for (int r = 0; r < 4; r++) {
                int gm = m0 + wm + i * 16 + quad * 4 + r;
                int gn = n0 + wn + j * 16 + l15;
                Cout[(size_t)gm * D_MODEL + gn] = acc[i][j][r] + bo[gn];
            }
}

// ---- flash attention: one block = one (b,h) x 64-query tile; 64-key tiles ----
// R8 structure (LDS-staged K/V, reg-prefetch pipeline, no-max exp2 softmax,
// wave-private P) with the q-tile halved: grid 1024 blocks -> 4 blocks/CU
// (16 waves/CU, ~50% occupancy vs R8's grid-capped 2 blocks/CU at 22%).
// LDS 27.6 KB. blockIdx.x = bh -> q-tiles of one bh share id%8 (XCD L2).
__global__ __launch_bounds__(256) void attn_kernel(
    const bf16_t* __restrict__ Qh, const bf16_t* __restrict__ Kh,
    const bf16_t* __restrict__ Vt, bf16_t* __restrict__ Oc) {

    __shared__ __align__(16) bf16_t Ks[64][LDP];    // K tile [key][dk]
    __shared__ __align__(16) bf16_t Vts[64][LDP];   // V^T tile [dk][key]
    __shared__ __align__(16) bf16_t Pls[64][LDP];   // P (wave-private 16-row regions); O epilogue

    const int tid = threadIdx.x, lane = tid & 63, wid = tid >> 6;
    const int l15 = lane & 15, quad = lane >> 4;
    const int bh = blockIdx.x;                 // XCD-friendly
    const int q0 = blockIdx.y * 64;
    const bf16_t* Qbase = Qh + (size_t)bh * SEQ * DK;
    const bf16_t* Kbase = Kh + (size_t)bh * SEQ * DK;
    const bf16_t* Vbase = Vt + (size_t)bh * DK * SEQ;
    const int srow = tid >> 3, scol = (tid & 7) << 3;

    // Q fragments: wave wid owns query rows [q0+wid*16, +16)
    bf16x8 aQ[2];
    #pragma unroll
    for (int c = 0; c < 2; c++)
        aQ[c] = ldfrag(Qbase + (size_t)(q0 + wid * 16 + l15) * DK + c * 32 + quad * 8);

    f32x4 oacc[4];
    #pragma unroll
    for (int j = 0; j < 4; j++) oacc[j] = zero4();
    float l_i[4] = {0.f, 0.f, 0.f, 0.f};

    uint4 rk[2], rv[2];
    #pragma unroll
    for (int t = 0; t < 2; t++) {
        int row = srow + 32 * t;
        rk[t] = *reinterpret_cast<const uint4*>(Kbase + (size_t)row * DK + scol);
        rv[t] = *reinterpret_cast<const uint4*>(Vbase + (size_t)row * SEQ + scol);
    }

    for (int kt = 0; kt < SEQ / 64; kt++) {
        __syncthreads();   // prev-iter reads of Ks/Vts done
        #pragma unroll
        for (int t = 0; t < 2; t++) {
            int row = srow + 32 * t;
            *reinterpret_cast<uint4*>(&Ks[row][scol])  = rk[t];
            *reinterpret_cast<uint4*>(&Vts[row][scol]) = rv[t];
        }
        __syncthreads();
        if (kt + 1 < SEQ / 64) {
            const int k1 = (kt + 1) * 64;
            #pragma unroll
            for (int t = 0; t < 2; t++) {
                int row = srow + 32 * t;
                rk[t] = *reinterpret_cast<const uint4*>(Kbase + (size_t)(k1 + row) * DK + scol);
                rv[t] = *reinterpret_cast<const uint4*>(Vbase + (size_t)row * SEQ + k1 + scol);
            }
        }

        // S = Q*K^T (Q pre-scaled by log2e/8)
        f32x4 sacc[4];
        #pragma unroll
        for (int j = 0; j < 4; j++) sacc[j] = zero4();
        #pragma unroll
        for (int c = 0; c < 2; c++) {
            bf16x8 bk4[4];
            #pragma unroll
            for (int j = 0; j < 4; j++) bk4[j] = ldfrag(&Ks[j * 16 + l15][c * 32 + quad * 8]);
            #pragma unroll
            for (int j = 0; j < 4; j++)
                sacc[j] = __builtin_amdgcn_mfma_f32_16x16x32_bf16(
                    aQ[c], bk4[j], sacc[j], 0, 0, 0);
        }

        // exp2, partial row sums, P -> wave-private LDS rows (no barrier)
        #pragma unroll
        for (int r = 0; r < 4; r++) {
            float e0 = exp2f(sacc[0][r]);
            float e1 = exp2f(sacc[1][r]);
            float e2 = exp2f(sacc[2][r]);
            float e3 = exp2f(sacc[3][r]);
            l_i[r] += (e0 + e1) + (e2 + e3);
            bf16_t* prow = &Pls[wid * 16 + quad * 4 + r][0];
            prow[l15]      = (bf16_t)e0;
            prow[16 + l15] = (bf16_t)e1;
            prow[32 + l15] = (bf16_t)e2;
            prow[48 + l15] = (bf16_t)e3;
        }

        // O += P*V (same-wave LDS write->read; compiler inserts lgkmcnt wait)
        #pragma unroll
        for (int c = 0; c < 2; c++) {
            bf16x8 ap = ldfrag(&Pls[wid * 16 + l15][c * 32 + quad * 8]);
            bf16x8 bv4[4];
            #pragma unroll
            for (int j = 0; j < 4; j++)
                bv4[j] = ldfrag(&Vts[j * 16 + l15][c * 32 + quad * 8]);
            #pragma unroll
            for (int j = 0; j < 4; j++)
                oacc[j] = __builtin_amdgcn_mfma_f32_16x16x32_bf16(
                    ap, bv4[j], oacc[j], 0, 0, 0);
        }
    }

    // normalize, stage into Pls, then coalesced 16B stores
    #pragma unroll
    for (int r = 0; r < 4; r++) {
        float l = l_i[r];
        #pragma unroll
        for (int off = 1; off < 16; off <<= 1)
            l += __shfl_xor(l, off, 64);
        float inv = 1.0f / l;
        #pragma unroll
        for (int j = 0; j < 4; j++)
            Pls[wid * 16 + quad * 4 + r][j * 16 + l15] = (bf16_t)(oacc[j][r] * inv);
    }
    __syncthreads();

    const int b = bh >> 4, h = bh & 15;
    #pragma unroll
    for (int c = tid; c < 512; c += 256) {   // 64 rows x 8 chunks of 8 bf16
        int row = c >> 3, col8 = (c & 7) << 3;
        uint4 val = *reinterpret_cast<const uint4*>(&Pls[row][col8]);
        *reinterpret_cast<uint4*>(Oc + ((size_t)(b * SEQ + q0 + row)) * D_MODEL + h * DK + col8) = val;
    }
}

extern "C" void kernel_launch(void* const* d_in, const int* in_sizes, int n_in,
                              void* d_out, int out_size, void* d_ws, size_t ws_size,
                              hipStream_t stream) {
    const float* q  = (const float*)d_in[0];
    const float* k  = (const float*)d_in[1];
    const float* v  = (const float*)d_in[2];
    const float* Wq = (const float*)d_in[3];
    const float* bq = (const float*)d_in[4];
    const float* Wk = (const float*)d_in[5];
    const float* bk = (const float*)d_in[6];
    const float* Wv = (const float*)d_in[7];
    const float* bv = (const float*)d_in[8];
    const float* Wo = (const float*)d_in[9];
    const float* bo = (const float*)d_in[10];

    const size_t nx = (size_t)MROWS * D_MODEL;   // 4,194,304
    const size_t nw = (size_t)D_MODEL * D_MODEL; // 1,048,576

    bf16_t* qb  = (bf16_t*)d_ws;
    bf16_t* kb  = qb  + nx;
    bf16_t* vb  = kb  + nx;
    bf16_t* Wqb = vb  + nx;
    bf16_t* Wkb = Wqb + nw;
    bf16_t* Wvb = Wkb + nw;
    bf16_t* Wob = Wvb + nw;
    bf16_t* Qh  = Wob + nw;   // [BH][S][DK]
    bf16_t* Kh  = Qh  + nx;   // [BH][S][DK]
    bf16_t* Vt  = Kh  + nx;   // [BH][DK][S]
    bf16_t* Oc  = Vt  + nx;   // [B*S][D]

    pack3<<<dim3(4096, 3), 256, 0, stream>>>(q, k, v, qb, kb, vb);
    pack4<<<dim3(1024, 4), 256, 0, stream>>>(Wq, Wk, Wv, Wo, Wqb, Wkb, Wvb, Wob);

    proj_gemm<<<dim3(8, 32, 3), 256, 0, stream>>>(qb, kb, vb, Wqb, Wkb, Wvb, bq, bk, bv, Qh, Kh, Vt);
    attn_kernel<<<dim3(32, 32), 256, 0, stream>>>(Qh, Kh, Vt, Oc);
    out_gemm<<<dim3(8, 32), 256, 0, stream>>>(Oc, Wob, bo, (float*)d_out);
}

// Round 10
// 250.213 us; speedup vs baseline: 1.2857x; 1.2857x over previous
//
#include <hip/hip_runtime.h>
#include <hip/hip_bf16.h>
#include <math.h>

// ---- types ----
typedef __bf16 bf16_t;
typedef bf16_t bf16x8 __attribute__((ext_vector_type(8)));
typedef float f32x4 __attribute__((ext_vector_type(4)));

#define D_MODEL 1024
#define NH 16
#define DK 64
#define SEQ 2048
#define MROWS 4096   // B*S
#define LDP 72       // padded LDS row (bf16) for per-lane-written attn tiles
#define LDSW 64      // UNPADDED row width for async-DMA tiles (XOR-swizzled)
#define LDC 136      // padded row for the 128x128 epilogue staging tile

__device__ __forceinline__ bf16x8 ldfrag(const bf16_t* p) {
    union { uint4 u; bf16x8 v; } c;
    c.u = *reinterpret_cast<const uint4*>(p);
    return c.v;
}

__device__ __forceinline__ f32x4 zero4() { f32x4 z = {0.f, 0.f, 0.f, 0.f}; return z; }

// async global->LDS DMA, 16B per lane. LDS dest = wave-uniform base + lane*16.
// No staging VGPRs -> immune to the compiler's VGPR-heuristic spills
// (R4/R7/R9 all lost 300-400 MB/launch to scratch writebacks from reg staging).
__device__ __forceinline__ void gll16(const bf16_t* g, bf16_t* l) {
    __builtin_amdgcn_global_load_lds(
        (const __attribute__((address_space(1))) unsigned int*)g,
        (__attribute__((address_space(3))) unsigned int*)l,
        16, 0, 0);
}

// ---- fp32 -> bf16 pack, 3 tensors via blockIdx.y ----
__global__ void pack3(const float* __restrict__ a, const float* __restrict__ b,
                      const float* __restrict__ c,
                      bf16_t* __restrict__ da, bf16_t* __restrict__ db, bf16_t* __restrict__ dc) {
    const float* s = (blockIdx.y == 0) ? a : (blockIdx.y == 1) ? b : c;
    bf16_t* d      = (blockIdx.y == 0) ? da : (blockIdx.y == 1) ? db : dc;
    int i = (blockIdx.x * blockDim.x + threadIdx.x) * 4;
    float4 f = *reinterpret_cast<const float4*>(s + i);
    union { bf16_t h[4]; uint2 u; } o;
    o.h[0] = (bf16_t)f.x; o.h[1] = (bf16_t)f.y; o.h[2] = (bf16_t)f.z; o.h[3] = (bf16_t)f.w;
    *reinterpret_cast<uint2*>(d + i) = o.u;
}

// ---- fp32 -> bf16 pack, 4 weight matrices via blockIdx.y ----
__global__ void pack4(const float* __restrict__ a, const float* __restrict__ b,
                      const float* __restrict__ c, const float* __restrict__ e,
                      bf16_t* __restrict__ da, bf16_t* __restrict__ db,
                      bf16_t* __restrict__ dc, bf16_t* __restrict__ de) {
    const float* s = (blockIdx.y == 0) ? a : (blockIdx.y == 1) ? b : (blockIdx.y == 2) ? c : e;
    bf16_t* d      = (blockIdx.y == 0) ? da : (blockIdx.y == 1) ? db : (blockIdx.y == 2) ? dc : de;
    int i = (blockIdx.x * blockDim.x + threadIdx.x) * 4;
    float4 f = *reinterpret_cast<const float4*>(s + i);
    union { bf16_t h[4]; uint2 u; } o;
    o.h[0] = (bf16_t)f.x; o.h[1] = (bf16_t)f.y; o.h[2] = (bf16_t)f.z; o.h[3] = (bf16_t)f.w;
    *reinterpret_cast<uint2*>(d + i) = o.u;
}

// ---- shared GEMM core: C(128x128) = A(rowmaj MxK) * B(rowmaj NxK)^T ----
// m97 structure: async global_load_lds staging; unpadded [128][64] tiles with
// XOR 16B-chunk swizzle (phys chunk p of row r holds logical chunk p^(r&7)).
__device__ __forceinline__ void gemm_core(
    const bf16_t* __restrict__ A, const bf16_t* __restrict__ Bm,
    int K, int m0, int n0,
    bf16_t* As, bf16_t* Bs,       // each 128*LDSW bf16
    f32x4 acc[4][4]) {

    const int tid = threadIdx.x;
    const int lane = tid & 63;
    const int wid = tid >> 6;
    const int wm = (wid >> 1) * 64, wn = (wid & 1) * 64;
    const int l15 = lane & 15, quad = lane >> 4;

    const int lrow   = lane >> 3;                // 0..7 row within 8-row group
    const int gcol   = ((lane & 7) ^ lrow) * 8;  // swizzled logical col (elems)

    #pragma unroll
    for (int i = 0; i < 4; i++)
        #pragma unroll
        for (int j = 0; j < 4; j++) acc[i][j] = zero4();

    for (int k0 = 0; k0 < K; k0 += 64) {
        __syncthreads();
        #pragma unroll
        for (int t = 0; t < 4; t++) {
            const int rbase = wid * 32 + t * 8;
            gll16(A  + (size_t)(m0 + rbase + lrow) * K + k0 + gcol, As + rbase * LDSW);
            gll16(Bm + (size_t)(n0 + rbase + lrow) * K + k0 + gcol, Bs + rbase * LDSW);
        }
        __syncthreads();
        #pragma unroll
        for (int c = 0; c < 2; c++) {
            bf16x8 af[4], bfr[4];
            #pragma unroll
            for (int i = 0; i < 4; i++) {
                const int row = wm + i * 16 + l15;
                const int pc = ((c * 4 + quad) ^ (l15 & 7)) * 8;
                af[i] = ldfrag(As + row * LDSW + pc);
            }
            #pragma unroll
            for (int j = 0; j < 4; j++) {
                const int row = wn + j * 16 + l15;
                const int pc = ((c * 4 + quad) ^ (l15 & 7)) * 8;
                bfr[j] = ldfrag(Bs + row * LDSW + pc);
            }
            #pragma unroll
            for (int i = 0; i < 4; i++)
                #pragma unroll
                for (int j = 0; j < 4; j++)
                    acc[i][j] = __builtin_amdgcn_mfma_f32_16x16x32_bf16(af[i], bfr[j], acc[i][j], 0, 0, 0);
        }
    }
}

// ---- fused Q/K/V projection: blockIdx.z picks which ----
__global__ __launch_bounds__(256, 2) void proj_gemm(
    const bf16_t* __restrict__ qb, const bf16_t* __restrict__ kb,
    const bf16_t* __restrict__ vb,
    const bf16_t* __restrict__ Wq, const bf16_t* __restrict__ Wk,
    const bf16_t* __restrict__ Wv,
    const float* __restrict__ bq, const float* __restrict__ bk, const float* __restrict__ bv,
    bf16_t* __restrict__ Qh, bf16_t* __restrict__ Kh, bf16_t* __restrict__ Vt) {

    __shared__ __align__(16) bf16_t sm[128 * LDC];   // 34816B: As|Bs, reused as Cs
    bf16_t* As = sm;
    bf16_t* Bs = sm + 128 * LDSW;
    bf16_t (*Cs)[LDC] = reinterpret_cast<bf16_t(*)[LDC]>(sm);
    f32x4 acc[4][4];

    const int mode = blockIdx.z;
    const bf16_t* X = (mode == 0) ? qb : (mode == 1) ? kb : vb;
    const bf16_t* W = (mode == 0) ? Wq : (mode == 1) ? Wk : Wv;
    const float* bias = (mode == 0) ? bq : (mode == 1) ? bk : bv;
    const int m0 = blockIdx.y * 128, n0 = blockIdx.x * 128;

    gemm_core(X, W, D_MODEL, m0, n0, As, Bs, acc);

    const int tid = threadIdx.x, lane = tid & 63, wid = tid >> 6;
    const int wm = (wid >> 1) * 64, wn = (wid & 1) * 64;
    const int l15 = lane & 15, quad = lane >> 4;

    __syncthreads();
    if (mode != 2) {
        // Q gets 1/sqrt(dk) * log2(e) folded in so attn can use raw exp2
        const float sc = (mode == 0) ? 0.125f * 1.44269504f : 1.0f;
        #pragma unroll
        for (int i = 0; i < 4; i++)
            #pragma unroll
            for (int j = 0; j < 4; j++)
                #pragma unroll
                for (int r = 0; r < 4; r++) {
                    int gn = n0 + wn + j * 16 + l15;
                    Cs[wm + i * 16 + quad * 4 + r][wn + j * 16 + l15] =
                        (bf16_t)((acc[i][j][r] + bias[gn]) * sc);
                }
    } else {
        #pragma unroll
        for (int i = 0; i < 4; i++)
            #pragma unroll
            for (int j = 0; j < 4; j++)
                #pragma unroll
                for (int r = 0; r < 4; r++) {
                    int gn = n0 + wn + j * 16 + l15;
                    Cs[wn + j * 16 + l15][wm + i * 16 + quad * 4 + r] =
                        (bf16_t)(acc[i][j][r] + bias[gn]);
                }
    }
    __syncthreads();

    #pragma unroll
    for (int c = tid; c < 2048; c += 256) {
        int row = c >> 4, col8 = (c & 15) << 3;
        uint4 val = *reinterpret_cast<const uint4*>(&Cs[row][col8]);
        if (mode != 2) {
            int gm = m0 + row, gn = n0 + col8;
            int b = gm >> 11, seq = gm & 2047;
            int h = gn >> 6, dk = gn & 63;
            bf16_t* dst = (mode == 0) ? Qh : Kh;
            *reinterpret_cast<uint4*>(dst + ((size_t)(b * NH + h) * SEQ + seq) * DK + dk) = val;
        } else {
            int gn = n0 + row, gm = m0 + col8;
            int b = gm >> 11, seq = gm & 2047;
            int h = gn >> 6, dk = gn & 63;
            *reinterpret_cast<uint4*>(Vt + ((size_t)(b * NH + h) * DK + dk) * SEQ + seq) = val;
        }
    }
}

// ---- output projection: fp32 out + bias ----
__global__ __launch_bounds__(256, 2) void out_gemm(
    const bf16_t* __restrict__ Oc, const bf16_t* __restrict__ Wo,
    const float* __restrict__ bo, float* __restrict__ Cout) {

    __shared__ __align__(16) bf16_t As[128 * LDSW];
    __shared__ __align__(16) bf16_t Bs[128 * LDSW];
    f32x4 acc[4][4];
    const int m0 = blockIdx.y * 128, n0 = blockIdx.x * 128;

    gemm_core(Oc, Wo, D_MODEL, m0, n0, As, Bs, acc);

    const int tid = threadIdx.x, lane = tid & 63, wid = tid >> 6;
    const int wm = (wid >> 1) * 64, wn = (wid & 1) * 64;
    const int l15 = lane & 15, quad = lane >> 4;

    #pragma unroll
    for (int i = 0; i < 4; i++)
        #pragma unroll
        for (int j = 0; j < 4; j++)
            #pragma unroll
            for (int r = 0; r < 4; r++) {
                int gm = m0 + wm + i * 16 + quad * 4 + r;
                int gn = n0 + wn + j * 16 + l15;
                Cout[(size_t)gm * D_MODEL + gn] = acc[i][j][r] + bo[gn];
            }
}

// ---- flash attention: one block = one (b,h) x 64-query tile; 64-key tiles ----
// R9 geometry (1024 blocks -> 4 blocks/CU, 43% occupancy — verified) but K/V
// staged via async global_load_lds into unpadded XOR-swizzled [64][64] tiles:
// zero staging VGPRs -> the compiler cannot spill them (R9: VGPR-52 heuristic
// spilled 317 MB). Pls stays padded (per-lane writes). LDS ~25 KB.
__global__ __launch_bounds__(256) void attn_kernel(
    const bf16_t* __restrict__ Qh, const bf16_t* __restrict__ Kh,
    const bf16_t* __restrict__ Vt, bf16_t* __restrict__ Oc) {

    __shared__ __align__(16) bf16_t Ks[64 * LDSW];    // K tile [key][dk], swizzled
    __shared__ __align__(16) bf16_t Vts[64 * LDSW];   // V^T tile [dk][key], swizzled
    __shared__ __align__(16) bf16_t Pls[64][LDP];     // P (wave-private 16-row regions); O epilogue

    const int tid = threadIdx.x, lane = tid & 63, wid = tid >> 6;
    const int l15 = lane & 15, quad = lane >> 4;
    const int bh = blockIdx.x;                 // XCD-friendly
    const int q0 = blockIdx.y * 64;
    const bf16_t* Qbase = Qh + (size_t)bh * SEQ * DK;
    const bf16_t* Kbase = Kh + (size_t)bh * SEQ * DK;
    const bf16_t* Vbase = Vt + (size_t)bh * DK * SEQ;

    const int lrow = lane >> 3;                  // 0..7 row within 8-row group
    const int gcol = ((lane & 7) ^ lrow) * 8;    // swizzled logical col (elems)

    // Q fragments: wave wid owns query rows [q0+wid*16, +16)
    bf16x8 aQ[2];
    #pragma unroll
    for (int c = 0; c < 2; c++)
        aQ[c] = ldfrag(Qbase + (size_t)(q0 + wid * 16 + l15) * DK + c * 32 + quad * 8);

    f32x4 oacc[4];
    #pragma unroll
    for (int j = 0; j < 4; j++) oacc[j] = zero4();
    float l_i[4] = {0.f, 0.f, 0.f, 0.f};

    for (int kt = 0; kt < SEQ / 64; kt++) {
        const int k0 = kt * 64;
        __syncthreads();   // prev-iter reads of Ks/Vts done
        // wave wid stages rows [wid*16, wid*16+16) of both tiles (2+2 DMA insts)
        #pragma unroll
        for (int t = 0; t < 2; t++) {
            const int rbase = wid * 16 + t * 8;
            gll16(Kbase + (size_t)(k0 + rbase + lrow) * DK + gcol,  Ks  + rbase * LDSW);
            gll16(Vbase + (size_t)(rbase + lrow) * SEQ + k0 + gcol, Vts + rbase * LDSW);
        }
        __syncthreads();   // barrier drains vmcnt -> DMA complete

        // S = Q*K^T (Q pre-scaled by log2e/8)
        f32x4 sacc[4];
        #pragma unroll
        for (int j = 0; j < 4; j++) sacc[j] = zero4();
        #pragma unroll
        for (int c = 0; c < 2; c++) {
            bf16x8 bk4[4];
            #pragma unroll
            for (int j = 0; j < 4; j++) {
                const int pc = ((c * 4 + quad) ^ (l15 & 7)) * 8;
                bk4[j] = ldfrag(Ks + (j * 16 + l15) * LDSW + pc);
            }
            #pragma unroll
            for (int j = 0; j < 4; j++)
                sacc[j] = __builtin_amdgcn_mfma_f32_16x16x32_bf16(
                    aQ[c], bk4[j], sacc[j], 0, 0, 0);
        }

        // exp2, partial row sums, P -> wave-private LDS rows (no barrier)
        #pragma unroll
        for (int r = 0; r < 4; r++) {
            float e0 = exp2f(sacc[0][r]);
            float e1 = exp2f(sacc[1][r]);
            float e2 = exp2f(sacc[2][r]);
            float e3 = exp2f(sacc[3][r]);
            l_i[r] += (e0 + e1) + (e2 + e3);
            bf16_t* prow = &Pls[wid * 16 + quad * 4 + r][0];
            prow[l15]      = (bf16_t)e0;
            prow[16 + l15] = (bf16_t)e1;
            prow[32 + l15] = (bf16_t)e2;
            prow[48 + l15] = (bf16_t)e3;
        }

        // O += P*V (same-wave LDS write->read; compiler inserts lgkmcnt wait)
        #pragma unroll
        for (int c = 0; c < 2; c++) {
            bf16x8 ap = ldfrag(&Pls[wid * 16 + l15][c * 32 + quad * 8]);
            bf16x8 bv4[4];
            #pragma unroll
            for (int j = 0; j < 4; j++) {
                const int pc = ((c * 4 + quad) ^ (l15 & 7)) * 8;
                bv4[j] = ldfrag(Vts + (j * 16 + l15) * LDSW + pc);
            }
            #pragma unroll
            for (int j = 0; j < 4; j++)
                oacc[j] = __builtin_amdgcn_mfma_f32_16x16x32_bf16(
                    ap, bv4[j], oacc[j], 0, 0, 0);
        }
    }

    // normalize, stage into Pls, then coalesced 16B stores
    #pragma unroll
    for (int r = 0; r < 4; r++) {
        float l = l_i[r];
        #pragma unroll
        for (int off = 1; off < 16; off <<= 1)
            l += __shfl_xor(l, off, 64);
        float inv = 1.0f / l;
        #pragma unroll
        for (int j = 0; j < 4; j++)
            Pls[wid * 16 + quad * 4 + r][j * 16 + l15] = (bf16_t)(oacc[j][r] * inv);
    }
    __syncthreads();

    const int b = bh >> 4, h = bh & 15;
    #pragma unroll
    for (int c = tid; c < 512; c += 256) {   // 64 rows x 8 chunks of 8 bf16
        int row = c >> 3, col8 = (c & 7) << 3;
        uint4 val = *reinterpret_cast<const uint4*>(&Pls[row][col8]);
        *reinterpret_cast<uint4*>(Oc + ((size_t)(b * SEQ + q0 + row)) * D_MODEL + h * DK + col8) = val;
    }
}

extern "C" void kernel_launch(void* const* d_in, const int* in_sizes, int n_in,
                              void* d_out, int out_size, void* d_ws, size_t ws_size,
                              hipStream_t stream) {
    const float* q  = (const float*)d_in[0];
    const float* k  = (const float*)d_in[1];
    const float* v  = (const float*)d_in[2];
    const float* Wq = (const float*)d_in[3];
    const float* bq = (const float*)d_in[4];
    const float* Wk = (const float*)d_in[5];
    const float* bk = (const float*)d_in[6];
    const float* Wv = (const float*)d_in[7];
    const float* bv = (const float*)d_in[8];
    const float* Wo = (const float*)d_in[9];
    const float* bo = (const float*)d_in[10];

    const size_t nx = (size_t)MROWS * D_MODEL;   // 4,194,304
    const size_t nw = (size_t)D_MODEL * D_MODEL; // 1,048,576

    bf16_t* qb  = (bf16_t*)d_ws;
    bf16_t* kb  = qb  + nx;
    bf16_t* vb  = kb  + nx;
    bf16_t* Wqb = vb  + nx;
    bf16_t* Wkb = Wqb + nw;
    bf16_t* Wvb = Wkb + nw;
    bf16_t* Wob = Wvb + nw;
    bf16_t* Qh  = Wob + nw;   // [BH][S][DK]
    bf16_t* Kh  = Qh  + nx;   // [BH][S][DK]
    bf16_t* Vt  = Kh  + nx;   // [BH][DK][S]
    bf16_t* Oc  = Vt  + nx;   // [B*S][D]

    pack3<<<dim3(4096, 3), 256, 0, stream>>>(q, k, v, qb, kb, vb);
    pack4<<<dim3(1024, 4), 256, 0, stream>>>(Wq, Wk, Wv, Wo, Wqb, Wkb, Wvb, Wob);

    proj_gemm<<<dim3(8, 32, 3), 256, 0, stream>>>(qb, kb, vb, Wqb, Wkb, Wvb, bq, bk, bv, Qh, Kh, Vt);
    attn_kernel<<<dim3(32, 32), 256, 0, stream>>>(Qh, Kh, Vt, Oc);
    out_gemm<<<dim3(8, 32), 256, 0, stream>>>(Oc, Wob, bo, (float*)d_out);
}